// Round 12
// baseline (2156.771 us; speedup 1.0000x reference)
//
#include <hip/hip_runtime.h>

#define NPTS 8192
#define NP   2048
#define NB   8
#define CIN  128
#define COUT 256
#define KNN_K 16
#define GQ_TOTAL (NB * NP)          // 16384
#define FB_GEMM_BLOCKS 512          // fallback path
#define FB_GEMM_QPB 32
#define CONS 248                    // consumer blocks in mega kernel
#define NTICK 2048                  // tickets = 8-query groups

typedef unsigned long long u64;
typedef float __attribute__((ext_vector_type(2))) f32x2;

__device__ __forceinline__ float mulrn(float a, float b){ return __fmul_rn(a,b); }
__device__ __forceinline__ float addrn(float a, float b){ return __fadd_rn(a,b); }
__device__ __forceinline__ float subrn(float a, float b){ return __fsub_rn(a,b); }

// coherent (sc1, LLC-level) accesses -- no cache-maintenance instructions.
__device__ __forceinline__ void coh_store_f(float* p, float v) {
  __hip_atomic_store((int*)p, __float_as_int(v), __ATOMIC_RELAXED,
                     __HIP_MEMORY_SCOPE_AGENT);
}
__device__ __forceinline__ float coh_load_f(const float* p) {
  int v = __hip_atomic_load((const int*)p, __ATOMIC_RELAXED,
                            __HIP_MEMORY_SCOPE_AGENT);
  return __int_as_float(v);
}

__device__ __forceinline__ u64 max_u64(u64 a, u64 b) { return (a > b) ? a : b; }

// one DPP butterfly level of a u64 max (value moves at VALU latency, not LDS).
template <int CTRL>
__device__ __forceinline__ u64 dpp_max_u64(u64 pk) {
  int lo = __builtin_amdgcn_update_dpp((int)(unsigned)(pk & 0xffffffffu),
                                       (int)(unsigned)(pk & 0xffffffffu),
                                       CTRL, 0xf, 0xf, false);
  int hi = __builtin_amdgcn_update_dpp((int)(unsigned)(pk >> 32),
                                       (int)(unsigned)(pk >> 32),
                                       CTRL, 0xf, 0xf, false);
  u64 o = ((u64)(unsigned)hi << 32) | (unsigned)lo;
  return (o > pk) ? o : pk;
}

struct FpsSm  { float4 p[NPTS]; u64 red[2][8]; };                           // 128.1 KB
struct ConsSm { float4 pts[NPTS]; float sg[2][16][132]; int sknn[8][16]; }; // 145 KB
union  MegaSm { FpsSm f; ConsSm c; };

// ---------------- FPS body (R3 structure, packed update, tree argmax) --------
// 512 threads, 16 pts/thread as 8 f32x2 pairs. In-thread argmax = u64 pair-max
// TREE (depth 4) over pk_j = (dist_bits<<32 | 8191-idx): same comparator as the
// DPP/LDS reduces -> bitwise-identical winner, ~100+ cyc less dependent latency
// than the serial select chain. DPP butterfly leaves wave max in lane 63.
template <bool PUB>
__device__ __forceinline__ void fps_body(const float* __restrict__ base,
    float* __restrict__ outb, FpsSm& S, int* prog_b, const int tid) {
  const int lane = tid & 63;
  const int wid = tid >> 6;                 // 0..7
  f32x2 px2[8], py2[8], pz2[8], dist2[8];
  unsigned key[16];                         // 8191 - global idx (pair lo dword)
  const int i0 = tid * 16;
  {
    const float4* b4 = (const float4*)(base + (size_t)i0 * 3);  // 192B/thread
#pragma unroll
    for (int q = 0; q < 4; ++q) {
      float4 v0 = b4[q*3+0], v1 = b4[q*3+1], v2 = b4[q*3+2];
      px2[q*2+0] = f32x2{v0.x, v0.w};  py2[q*2+0] = f32x2{v0.y, v1.x};  pz2[q*2+0] = f32x2{v0.z, v1.y};
      px2[q*2+1] = f32x2{v1.z, v2.y};  py2[q*2+1] = f32x2{v1.w, v2.z};  pz2[q*2+1] = f32x2{v2.x, v2.w};
    }
  }
#pragma unroll
  for (int q = 0; q < 8; ++q) {
    S.p[i0 + 2*q + 0] = make_float4(px2[q].x, py2[q].x, pz2[q].x, 0.0f);
    S.p[i0 + 2*q + 1] = make_float4(px2[q].y, py2[q].y, pz2[q].y, 0.0f);
    dist2[q] = f32x2{1e10f, 1e10f};
    key[2*q + 0] = 8191u - (unsigned)(i0 + 2*q + 0);
    key[2*q + 1] = 8191u - (unsigned)(i0 + 2*q + 1);
  }
  if (tid == 0) {
    if (PUB) { coh_store_f(&outb[0], px2[0].x); coh_store_f(&outb[1], py2[0].x);
               coh_store_f(&outb[2], pz2[0].x); }
    else     { outb[0] = px2[0].x; outb[1] = py2[0].x; outb[2] = pz2[0].x; }
  }
  __syncthreads();
  float cx = S.p[0].x, cy = S.p[0].y, cz = S.p[0].z;

#pragma unroll 1
  for (int s = 1; s < NP; ++s) {
    const int p = s & 1;
    u64 m[8];
    {
#pragma clang fp contract(off)
      const f32x2 c2x = f32x2{cx, cx};
      const f32x2 c2y = f32x2{cy, cy};
      const f32x2 c2z = f32x2{cz, cz};
#pragma unroll
      for (int q = 0; q < 8; ++q) {
        f32x2 dx = px2[q] - c2x;             // v_pk_add (neg) : exact per half
        f32x2 dy = py2[q] - c2y;
        f32x2 dz = pz2[q] - c2z;
        f32x2 xx = dx * dx;                  // v_pk_mul
        f32x2 yy = dy * dy;
        f32x2 zz = dz * dz;
        f32x2 ss = (xx + yy) + zz;           // v_pk_add x2, reference order
        float dm0 = fminf(dist2[q].x, ss.x);
        float dm1 = fminf(dist2[q].y, ss.y);
        dist2[q].x = dm0; dist2[q].y = dm1;
        // pair formation (no ALU): hi = dist bits, lo = key
        u64 l0 = ((u64)__float_as_uint(dm0) << 32) | key[2*q + 0];
        u64 l1 = ((u64)__float_as_uint(dm1) << 32) | key[2*q + 1];
        m[q] = max_u64(l0, l1);              // tree level 1
      }
    }
    u64 a0 = max_u64(m[0], m[1]);
    u64 a1 = max_u64(m[2], m[3]);
    u64 a2 = max_u64(m[4], m[5]);
    u64 a3 = max_u64(m[6], m[7]);
    u64 pk = max_u64(max_u64(a0, a1), max_u64(a2, a3));
    pk = dpp_max_u64<0x111>(pk);             // row_shr:1
    pk = dpp_max_u64<0x112>(pk);             // row_shr:2
    pk = dpp_max_u64<0x114>(pk);             // row_shr:4
    pk = dpp_max_u64<0x118>(pk);             // row_shr:8
    pk = dpp_max_u64<0x142>(pk);             // row_bcast:15
    pk = dpp_max_u64<0x143>(pk);             // row_bcast:31  -> max in lane 63
    if (lane == 63) S.red[p][wid] = pk;
    __syncthreads();                         // the ONE barrier per step
    u64 t0=S.red[p][0], t1=S.red[p][1], t2=S.red[p][2], t3=S.red[p][3];
    u64 t4=S.red[p][4], t5=S.red[p][5], t6=S.red[p][6], t7=S.red[p][7];
    t0=(t1>t0)?t1:t0; t2=(t3>t2)?t3:t2; t4=(t5>t4)?t5:t4; t6=(t7>t6)?t7:t6;
    t0=(t2>t0)?t2:t0; t4=(t6>t4)?t6:t4;
    t0=(t4>t0)?t4:t0;
    const int ri = 8191 - (int)((unsigned)(t0 & 0xffffffffu));
    const float4 c = S.p[ri];                // single b128 broadcast
    cx = c.x; cy = c.y; cz = c.z;
    if (tid == 0) {
      const size_t o = (size_t)s * 3;
      if (PUB) {
        coh_store_f(&outb[o+0], cx); coh_store_f(&outb[o+1], cy);
        coh_store_f(&outb[o+2], cz);
        if ((s & 7) == 7) {
          asm volatile("s_waitcnt vmcnt(0)" ::: "memory");  // data stores visible
          __hip_atomic_store(prog_b, s + 1, __ATOMIC_RELAXED,
                             __HIP_MEMORY_SCOPE_AGENT);
        }
      } else {
        outb[o+0]=cx; outb[o+1]=cy; outb[o+2]=cz;
      }
    }
  }
  if (PUB && tid == 0) {
    asm volatile("s_waitcnt vmcnt(0)" ::: "memory");
    __hip_atomic_store(prog_b, NP, __ATOMIC_RELAXED, __HIP_MEMORY_SCOPE_AGENT);
  }
}

// ---------------- one-query KNN (one wave) -----------------------------------
__device__ __forceinline__ void knn_one(const float4* __restrict__ s_pts,
    const float qx, const float qy, const float qz, const int lane,
    int* __restrict__ gout, int* __restrict__ lout) {
  const float qn = addrn(addrn(mulrn(qx,qx), mulrn(qy,qy)), mulrn(qz,qz));
  float bd = (lane < 16) ? 1e30f : -1e30f;
  int   bi = 0;
  float r = 1e30f;
#pragma unroll 1
  for (int c0 = 0; c0 < NPTS; c0 += 64) {
    float4 p = s_pts[c0 + lane];
    float dot = addrn(addrn(mulrn(qx, p.x), mulrn(qy, p.y)), mulrn(qz, p.z));
    float dd = addrn(addrn(mulrn(-2.0f, dot), qn), p.w);
    u64 m = __ballot(dd < r);
    while (m) {
      int src = __builtin_ctzll(m);
      m &= (m - 1);
      float v = __shfl(dd, src, 64);
      if (v < r) {
        int vi = c0 + src;
        float bdn = __shfl_down(bd, 1, 64);
        int   bin_ = __shfl_down(bi, 1, 64);
        bool c1 = bdn > v;
        bool c2 = bd > v;
        float nb  = c1 ? bdn  : (c2 ? v  : bd);
        int   nbi = c1 ? bin_ : (c2 ? vi : bi);
        bd = (lane < 16) ? nb  : -1e30f;
        bi = (lane < 16) ? nbi : bi;
        r = __shfl(bd, 0, 64);
      }
    }
  }
  if (lane < 16) {
    if (gout) gout[lane] = bi;
    if (lout) lout[lane] = bi;
  }
}

// ---------------- MEGA: producers + consumers + in-kernel stats/finalize -----
// prog[0..7]  : per-batch FPS progress
// prog[8]     : consumer arrival counter (all tickets + partials done)
// prog[9]     : scale/bias-ready flag
__global__ __launch_bounds__(512) void k_mega(const float* __restrict__ xyz,
    const float* __restrict__ feat, const float* __restrict__ W,
    const float* __restrict__ gamma, const float* __restrict__ beta,
    float* __restrict__ out_xyz, float* __restrict__ out_nf,
    int* __restrict__ knn,
    float* __restrict__ part_sum, float* __restrict__ part_sq,
    float* __restrict__ hmax_buf, float* __restrict__ hmin_buf,
    float* __restrict__ scale, float* __restrict__ bias,
    int* __restrict__ prog) {
  __shared__ MegaSm sm;
  const int tid = threadIdx.x;
  if (blockIdx.x < NB) {
    const int b = blockIdx.x;
    fps_body<true>(xyz + (size_t)b * NPTS * 3, out_xyz + (size_t)b * NP * 3,
                   sm.f, &prog[b], tid);
    return;
  }
  // ---- consumer ----
  const int c = blockIdx.x - NB;           // 0..247
  const int b = c & 7;                     // fixed batch per block
  ConsSm& S = sm.c;
  const float* base = xyz + (size_t)b * NPTS * 3;
  for (int i = tid; i < NPTS; i += 512) {
    float x = base[i*3+0], y = base[i*3+1], z = base[i*3+2];
    float n = addrn(addrn(mulrn(x,x), mulrn(y,y)), mulrn(z,z));
    S.pts[i] = make_float4(x, y, z, n);
  }
  const int d = tid & 255;
  const int h = tid >> 8;                  // half 0/1
  float w[132];
#pragma unroll
  for (int cc = 0; cc < 132; ++cc) {
    if (cc < 128)      w[cc] = W[(size_t)(3 + cc) * COUT + d];
    else if (cc < 131) w[cc] = W[(size_t)(cc - 128) * COUT + d];
    else               w[cc] = 0.0f;
  }
  float psum = 0.0f, psq = 0.0f;
  const int lane = tid & 63;
  const int wv = tid >> 6;                 // 0..7
  __syncthreads();
#pragma unroll 1
  for (int t = c; t < NTICK; t += CONS) {
    const int g = t >> 3;                  // qgroup; (t&7)==b by construction
    const int need = g * 8 + 8;
    if (tid == 0) {
      while (__hip_atomic_load(&prog[b], __ATOMIC_RELAXED,
                               __HIP_MEMORY_SCOPE_AGENT) < need)
        __builtin_amdgcn_s_sleep(16);
    }
    __syncthreads();
    {   // knn: one query per wave; query coords via coherent loads
      const int gq = b * NP + g * 8 + wv;
      const float qx = coh_load_f(&out_xyz[(size_t)gq*3+0]);
      const float qy = coh_load_f(&out_xyz[(size_t)gq*3+1]);
      const float qz = coh_load_f(&out_xyz[(size_t)gq*3+2]);
      knn_one(S.pts, qx, qy, qz, lane, &knn[(size_t)gq * KNN_K], &S.sknn[wv][0]);
    }
    __syncthreads();
    // gemm mode0 for the 8 queries: half h does 4
#pragma unroll 1
    for (int i = 0; i < 4; ++i) {
      const int ql = h * 4 + i;
      const int gq = b * NP + g * 8 + ql;
      {
        const int row = d >> 4, sub = d & 15;
        const int nidx = S.sknn[ql][row];
        const float* frow = feat + ((size_t)b * NPTS + nidx) * CIN;
        const float4 a0 = *(const float4*)(frow + sub * 8);
        const float4 a1 = *(const float4*)(frow + sub * 8 + 4);
        *(float4*)&S.sg[h][row][sub * 8]     = a0;
        *(float4*)&S.sg[h][row][sub * 8 + 4] = a1;
        if (sub == 0) {
          const float gx = xyz[((size_t)b * NPTS + nidx) * 3 + 0];
          const float gy = xyz[((size_t)b * NPTS + nidx) * 3 + 1];
          const float gz = xyz[((size_t)b * NPTS + nidx) * 3 + 2];
          const float qx = coh_load_f(&out_xyz[(size_t)gq*3+0]);
          const float qy = coh_load_f(&out_xyz[(size_t)gq*3+1]);
          const float qz = coh_load_f(&out_xyz[(size_t)gq*3+2]);
          *(float4*)&S.sg[h][row][128] = make_float4(gx-qx, gy-qy, gz-qz, 0.0f);
        }
      }
      __syncthreads();
      float hmax = -1e30f, hmin = 1e30f;
#pragma unroll 1
      for (int k = 0; k < 16; ++k) {
        float a0 = 0.f, a1 = 0.f, a2 = 0.f, a3 = 0.f;
#pragma unroll
        for (int c4 = 0; c4 < 33; ++c4) {
          float4 gg = *(const float4*)&S.sg[h][k][c4 * 4];
          a0 = fmaf(gg.x, w[c4 * 4 + 0], a0);
          a1 = fmaf(gg.y, w[c4 * 4 + 1], a1);
          a2 = fmaf(gg.z, w[c4 * 4 + 2], a2);
          a3 = fmaf(gg.w, w[c4 * 4 + 3], a3);
        }
        float hv = (a0 + a1) + (a2 + a3);
        psum += hv; psq = fmaf(hv, hv, psq);
        hmax = fmaxf(hmax, hv); hmin = fminf(hmin, hv);
      }
      hmax_buf[(size_t)gq * COUT + d] = hmax;   // block-local: re-read below
      hmin_buf[(size_t)gq * COUT + d] = hmin;
      __syncthreads();
    }
  }
  // publish partials (sc1 -> LLC) and arrive at the software barrier
  coh_store_f(&part_sum[((size_t)c * 2 + h) * COUT + d], psum);
  coh_store_f(&part_sq [((size_t)c * 2 + h) * COUT + d], psq);
  asm volatile("s_waitcnt vmcnt(0)" ::: "memory");   // wave's stores at LLC
  __syncthreads();
  if (tid == 0)
    __hip_atomic_fetch_add(&prog[8], 1, __ATOMIC_RELAXED,
                           __HIP_MEMORY_SCOPE_AGENT);
  // consumer 0 computes scale/bias once all partials are published
  if (c == 0) {
    if (tid == 0) {
      while (__hip_atomic_load(&prog[8], __ATOMIC_RELAXED,
                               __HIP_MEMORY_SCOPE_AGENT) < CONS)
        __builtin_amdgcn_s_sleep(16);
    }
    __syncthreads();
    if (tid < 256) {
      float s = 0.0f, q = 0.0f;
#pragma unroll 1
      for (int r = 0; r < CONS * 2; ++r) {
        s += coh_load_f(&part_sum[(size_t)r * COUT + tid]);
        q += coh_load_f(&part_sq [(size_t)r * COUT + tid]);
      }
      const float inv = 1.0f / 262144.0f;
      float mean = s * inv;
      float var = q * inv - mean * mean;
      float scv = gamma[tid] / sqrtf(var + 1e-5f);
      coh_store_f(&scale[tid], scv);
      coh_store_f(&bias[tid], beta[tid] - mean * scv);
    }
    asm volatile("s_waitcnt vmcnt(0)" ::: "memory");
    __syncthreads();
    if (tid == 0)
      __hip_atomic_store(&prog[9], 1, __ATOMIC_RELAXED,
                         __HIP_MEMORY_SCOPE_AGENT);
  }
  // all consumers: wait for scale/bias, then finalize OWN rows (L2-local)
  if (tid == 0) {
    while (__hip_atomic_load(&prog[9], __ATOMIC_RELAXED,
                             __HIP_MEMORY_SCOPE_AGENT) < 1)
      __builtin_amdgcn_s_sleep(16);
  }
  __syncthreads();
  const float sc = coh_load_f(&scale[d]);
  const float bb = coh_load_f(&bias[d]);
#pragma unroll 1
  for (int t = c; t < NTICK; t += CONS) {
    const int g = t >> 3;
#pragma unroll
    for (int i = 0; i < 4; ++i) {
      const int gq = b * NP + g * 8 + h * 4 + i;
      const float hx = hmax_buf[(size_t)gq * COUT + d];
      const float hn = hmin_buf[(size_t)gq * COUT + d];
      const float hsel = (sc >= 0.0f) ? hx : hn;
      out_nf[(size_t)gq * COUT + d] = fmaxf(fmaf(sc, hsel, bb), 0.0f);
    }
  }
}

// ---------------- init: zero progress counters + barrier + flag --------------
__global__ void k_init(int* __restrict__ prog) {
  if (threadIdx.x < 16) prog[threadIdx.x] = 0;
}

// ---------------- standalone fallback kernels --------------------------------
__global__ __launch_bounds__(512) void k_fps(const float* __restrict__ xyz,
                                             float* __restrict__ out_xyz) {
  __shared__ FpsSm S;
  fps_body<false>(xyz + (size_t)blockIdx.x * NPTS * 3,
                  out_xyz + (size_t)blockIdx.x * NP * 3, S, nullptr, threadIdx.x);
}

__global__ __launch_bounds__(512) void k_knn(const float* __restrict__ xyz,
                                             const float* __restrict__ new_xyz,
                                             int* __restrict__ knn) {
  __shared__ float4 s_pts[NPTS];   // 128 KB
  const int gq0 = blockIdx.x * 64;
  const int b = gq0 >> 11;
  const float* base = xyz + (size_t)b * NPTS * 3;
  for (int i = threadIdx.x; i < NPTS; i += 512) {
    float x = base[i*3+0], y = base[i*3+1], z = base[i*3+2];
    float n = addrn(addrn(mulrn(x,x), mulrn(y,y)), mulrn(z,z));
    s_pts[i] = make_float4(x, y, z, n);
  }
  __syncthreads();
  const int wave = threadIdx.x >> 6;
  const int lane = threadIdx.x & 63;
#pragma unroll 1
  for (int qi = 0; qi < 8; ++qi) {
    const int gq = gq0 + wave * 8 + qi;
    knn_one(s_pts, new_xyz[(size_t)gq*3+0], new_xyz[(size_t)gq*3+1],
            new_xyz[(size_t)gq*3+2], lane, &knn[(size_t)gq * KNN_K], nullptr);
  }
}

__global__ __launch_bounds__(256) void k_gemm(const float* __restrict__ feat,
    const float* __restrict__ xyz, const float* __restrict__ new_xyz,
    const int* __restrict__ knn, const float* __restrict__ W,
    float* __restrict__ part_sum, float* __restrict__ part_sq,
    float* __restrict__ hmax_buf, float* __restrict__ hmin_buf,
    const float* __restrict__ scale, const float* __restrict__ bias,
    float* __restrict__ out, int mode) {
  __shared__ float sg[16][132];
  const int d = threadIdx.x;
  float w[132];
#pragma unroll
  for (int c = 0; c < 132; ++c) {
    if (c < 128)      w[c] = W[(size_t)(3 + c) * COUT + d];
    else if (c < 131) w[c] = W[(size_t)(c - 128) * COUT + d];
    else              w[c] = 0.0f;
  }
  float psum = 0.0f, psq = 0.0f;
  float sc = 0.0f, bb = 0.0f;
  if (mode == 1) { sc = scale[d]; bb = bias[d]; }
#pragma unroll 1
  for (int i = 0; i < FB_GEMM_QPB; ++i) {
    const int gq = blockIdx.x * FB_GEMM_QPB + i;
    const int b = gq >> 11;
    {
      const int row = d >> 4, sub = d & 15;
      const int nidx = knn[(size_t)gq * KNN_K + row];
      const float* frow = feat + ((size_t)b * NPTS + nidx) * CIN;
      const float4 a0 = *(const float4*)(frow + sub * 8);
      const float4 a1 = *(const float4*)(frow + sub * 8 + 4);
      *(float4*)&sg[row][sub * 8]     = a0;
      *(float4*)&sg[row][sub * 8 + 4] = a1;
      if (sub == 0) {
        const float gx = xyz[((size_t)b * NPTS + nidx) * 3 + 0];
        const float gy = xyz[((size_t)b * NPTS + nidx) * 3 + 1];
        const float gz = xyz[((size_t)b * NPTS + nidx) * 3 + 2];
        const float qx = new_xyz[(size_t)gq * 3 + 0];
        const float qy = new_xyz[(size_t)gq * 3 + 1];
        const float qz = new_xyz[(size_t)gq * 3 + 2];
        *(float4*)&sg[row][128] = make_float4(gx - qx, gy - qy, gz - qz, 0.0f);
      }
    }
    __syncthreads();
    float hmax = -1e30f, hmin = 1e30f;
#pragma unroll 1
    for (int k = 0; k < 16; ++k) {
      float a0 = 0.f, a1 = 0.f, a2 = 0.f, a3 = 0.f;
#pragma unroll
      for (int c4 = 0; c4 < 33; ++c4) {
        float4 g = *(const float4*)&sg[k][c4 * 4];
        a0 = fmaf(g.x, w[c4 * 4 + 0], a0);
        a1 = fmaf(g.y, w[c4 * 4 + 1], a1);
        a2 = fmaf(g.z, w[c4 * 4 + 2], a2);
        a3 = fmaf(g.w, w[c4 * 4 + 3], a3);
      }
      float hv = (a0 + a1) + (a2 + a3);
      if (mode == 0) { psum += hv; psq = fmaf(hv, hv, psq); }
      hmax = fmaxf(hmax, hv); hmin = fminf(hmin, hv);
    }
    if (mode == 0) {
      if (hmax_buf) {
        hmax_buf[(size_t)gq * COUT + d] = hmax;
        hmin_buf[(size_t)gq * COUT + d] = hmin;
      }
    } else {
      float hsel = (sc >= 0.0f) ? hmax : hmin;
      out[(size_t)gq * COUT + d] = fmaxf(fmaf(sc, hsel, bb), 0.0f);
    }
    __syncthreads();
  }
  if (mode == 0) {
    part_sum[(size_t)blockIdx.x * COUT + d] = psum;
    part_sq [(size_t)blockIdx.x * COUT + d] = psq;
  }
}

// ---------------- stats fold (fallback) --------------------------------------
__global__ __launch_bounds__(256) void k_stats(const float* __restrict__ part_sum,
    const float* __restrict__ part_sq, const float* __restrict__ gamma,
    const float* __restrict__ beta, float* __restrict__ scale,
    float* __restrict__ bias, int nrows) {
  const int d = threadIdx.x;
  float s = 0.0f, q = 0.0f;
  for (int bl = 0; bl < nrows; ++bl) {
    s += part_sum[(size_t)bl * COUT + d];
    q += part_sq[(size_t)bl * COUT + d];
  }
  const float inv = 1.0f / 262144.0f;
  float mean = s * inv;
  float var = q * inv - mean * mean;
  float scv = gamma[d] / sqrtf(var + 1e-5f);
  scale[d] = scv;
  bias[d] = beta[d] - mean * scv;
}

// ---------------- elementwise finalize (fallback) ----------------------------
__global__ __launch_bounds__(256) void k_final(const float* __restrict__ hmax_buf,
    const float* __restrict__ hmin_buf, const float* __restrict__ scale,
    const float* __restrict__ bias, float* __restrict__ out) {
  const int e4 = (blockIdx.x * 256 + threadIdx.x) * 4;
  const int d0 = e4 & (COUT - 1);
  const float4 hx = *(const float4*)&hmax_buf[e4];
  const float4 hn = *(const float4*)&hmin_buf[e4];
  const float4 sc = *(const float4*)&scale[d0];
  const float4 bb = *(const float4*)&bias[d0];
  float4 o;
  o.x = fmaxf(fmaf(sc.x, (sc.x >= 0.f) ? hx.x : hn.x, bb.x), 0.f);
  o.y = fmaxf(fmaf(sc.y, (sc.y >= 0.f) ? hx.y : hn.y, bb.y), 0.f);
  o.z = fmaxf(fmaf(sc.z, (sc.z >= 0.f) ? hx.z : hn.z, bb.z), 0.f);
  o.w = fmaxf(fmaf(sc.w, (sc.w >= 0.f) ? hx.w : hn.w, bb.w), 0.f);
  *(float4*)&out[e4] = o;
}

extern "C" void kernel_launch(void* const* d_in, const int* in_sizes, int n_in,
                              void* d_out, int out_size, void* d_ws, size_t ws_size,
                              hipStream_t stream) {
  const float* xyz   = (const float*)d_in[0];
  const float* feat  = (const float*)d_in[1];
  const float* W     = (const float*)d_in[2];
  const float* gamma = (const float*)d_in[3];
  const float* beta  = (const float*)d_in[4];
  float* out_xyz = (float*)d_out;
  float* out_nf  = out_xyz + (size_t)NB * NP * 3;

  // workspace layout (~35.65 MB)
  char* ws = (char*)d_ws;
  int*   knn      = (int*)ws;                                        // 1 MB
  float* hmax_buf = (float*)(ws + (1 << 20));                        // 16.78 MB
  float* hmin_buf = (float*)(ws + (1 << 20) + (size_t)GQ_TOTAL*COUT*4);
  char*  ws3      = ws + (1 << 20) + 2ull * GQ_TOTAL * COUT * 4;
  float* part_sum = (float*)ws3;                                     // 512 KB
  float* part_sq  = (float*)(ws3 + (size_t)FB_GEMM_BLOCKS * COUT * 4);
  int*   prog     = (int*)(ws3 + 2ull * FB_GEMM_BLOCKS * COUT * 4);  // 64 B
  float* scale    = (float*)((char*)prog + 64);
  float* bias     = scale + COUT;
  const size_t need = (1ull << 20) + 2ull * GQ_TOTAL * COUT * 4
                    + 2ull * FB_GEMM_BLOCKS * COUT * 4 + 64 + 2 * COUT * 4;

  bool mega_ok = false;
  if (ws_size >= need) {
    hipLaunchKernelGGL(k_init, dim3(1), dim3(64), 0, stream, prog);
    void* args[] = {(void*)&xyz, (void*)&feat, (void*)&W,
                    (void*)&gamma, (void*)&beta,
                    (void*)&out_xyz, (void*)&out_nf, (void*)&knn,
                    (void*)&part_sum, (void*)&part_sq,
                    (void*)&hmax_buf, (void*)&hmin_buf,
                    (void*)&scale, (void*)&bias, (void*)&prog};
    hipError_t e = hipLaunchCooperativeKernel((const void*)k_mega, dim3(NB + CONS),
                                              dim3(512), args, 0, stream);
    mega_ok = (e == hipSuccess);
  }
  if (!mega_ok) {
    // sequential fallback (proven path)
    hipLaunchKernelGGL(k_fps, dim3(NB), dim3(512), 0, stream, xyz, out_xyz);
    hipLaunchKernelGGL(k_knn, dim3(256), dim3(512), 0, stream, xyz, out_xyz, knn);
    if (ws_size >= need) {
      hipLaunchKernelGGL(k_gemm, dim3(FB_GEMM_BLOCKS), dim3(256), 0, stream, feat,
                         xyz, out_xyz, knn, W, part_sum, part_sq, hmax_buf,
                         hmin_buf, (const float*)nullptr, (const float*)nullptr,
                         (float*)nullptr, 0);
      hipLaunchKernelGGL(k_stats, dim3(1), dim3(256), 0, stream, part_sum, part_sq,
                         gamma, beta, scale, bias, FB_GEMM_BLOCKS);
      hipLaunchKernelGGL(k_final, dim3(GQ_TOTAL * COUT / 1024), dim3(256), 0,
                         stream, hmax_buf, hmin_buf, scale, bias, out_nf);
    } else {
      float* f_ps = (float*)(ws + (1 << 20));
      float* f_pq = f_ps + FB_GEMM_BLOCKS * COUT;
      float* f_sc = f_pq + FB_GEMM_BLOCKS * COUT;
      float* f_bb = f_sc + COUT;
      hipLaunchKernelGGL(k_gemm, dim3(FB_GEMM_BLOCKS), dim3(256), 0, stream, feat,
                         xyz, out_xyz, knn, W, f_ps, f_pq, (float*)nullptr,
                         (float*)nullptr, (const float*)nullptr,
                         (const float*)nullptr, (float*)nullptr, 0);
      hipLaunchKernelGGL(k_stats, dim3(1), dim3(256), 0, stream, f_ps, f_pq,
                         gamma, beta, f_sc, f_bb, FB_GEMM_BLOCKS);
      hipLaunchKernelGGL(k_gemm, dim3(FB_GEMM_BLOCKS), dim3(256), 0, stream, feat,
                         xyz, out_xyz, knn, W, (float*)nullptr, (float*)nullptr,
                         (float*)nullptr, (float*)nullptr, f_sc, f_bb, out_nf, 1);
    }
  }
}

// Round 13
// 2092.864 us; speedup vs baseline: 1.0305x; 1.0305x over previous
//
#include <hip/hip_runtime.h>

#define NPTS 8192
#define NP   2048
#define NB   8
#define CIN  128
#define COUT 256
#define KNN_K 16
#define GQ_TOTAL (NB * NP)          // 16384
#define FB_GEMM_BLOCKS 512          // fallback path
#define FB_GEMM_QPB 32
#define CONS 248                    // consumer blocks in mega kernel
#define NTICK 2048                  // tickets = 8-query groups

typedef unsigned long long u64;
typedef float __attribute__((ext_vector_type(2))) f32x2;

__device__ __forceinline__ float mulrn(float a, float b){ return __fmul_rn(a,b); }
__device__ __forceinline__ float addrn(float a, float b){ return __fadd_rn(a,b); }
__device__ __forceinline__ float subrn(float a, float b){ return __fsub_rn(a,b); }

// coherent (sc1, LLC-level) accesses -- no cache-maintenance instructions.
__device__ __forceinline__ void coh_store_f(float* p, float v) {
  __hip_atomic_store((int*)p, __float_as_int(v), __ATOMIC_RELAXED,
                     __HIP_MEMORY_SCOPE_AGENT);
}
__device__ __forceinline__ float coh_load_f(const float* p) {
  int v = __hip_atomic_load((const int*)p, __ATOMIC_RELAXED,
                            __HIP_MEMORY_SCOPE_AGENT);
  return __int_as_float(v);
}

// one DPP butterfly level of a u64 max (value moves at VALU latency, not LDS).
template <int CTRL>
__device__ __forceinline__ u64 dpp_max_u64(u64 pk) {
  int lo = __builtin_amdgcn_update_dpp((int)(unsigned)(pk & 0xffffffffu),
                                       (int)(unsigned)(pk & 0xffffffffu),
                                       CTRL, 0xf, 0xf, false);
  int hi = __builtin_amdgcn_update_dpp((int)(unsigned)(pk >> 32),
                                       (int)(unsigned)(pk >> 32),
                                       CTRL, 0xf, 0xf, false);
  u64 o = ((u64)(unsigned)hi << 32) | (unsigned)lo;
  return (o > pk) ? o : pk;
}

struct FpsSm  { float4 p[NPTS]; u64 red[2][8]; };                           // 128.1 KB
struct ConsSm { float4 pts[NPTS]; float sg[2][16][132]; int sknn[8][16]; }; // 145 KB
union  MegaSm { FpsSm f; ConsSm c; };

// ---------------- FPS body (R3 structure, packed-f32 update, DPP reduce) -----
// 512 threads, 16 pts/thread as 8 f32x2 pairs. DPP max chain (row_shr 1/2/4/8,
// bcast15, bcast31) leaves the wave max of the packed u64 in lane 63 -- same
// comparisons as the shfl version, bitwise-identical winner.
template <bool PUB>
__device__ __forceinline__ void fps_body(const float* __restrict__ base,
    float* __restrict__ outb, FpsSm& S, int* prog_b, const int tid) {
  const int lane = tid & 63;
  const int wid = tid >> 6;                 // 0..7
  f32x2 px2[8], py2[8], pz2[8], dist2[8];
  const int i0 = tid * 16;
  {
    const float4* b4 = (const float4*)(base + (size_t)i0 * 3);  // 192B/thread
#pragma unroll
    for (int q = 0; q < 4; ++q) {
      float4 v0 = b4[q*3+0], v1 = b4[q*3+1], v2 = b4[q*3+2];
      px2[q*2+0] = f32x2{v0.x, v0.w};  py2[q*2+0] = f32x2{v0.y, v1.x};  pz2[q*2+0] = f32x2{v0.z, v1.y};
      px2[q*2+1] = f32x2{v1.z, v2.y};  py2[q*2+1] = f32x2{v1.w, v2.z};  pz2[q*2+1] = f32x2{v2.x, v2.w};
    }
  }
#pragma unroll
  for (int q = 0; q < 8; ++q) {
    S.p[i0 + 2*q + 0] = make_float4(px2[q].x, py2[q].x, pz2[q].x, 0.0f);
    S.p[i0 + 2*q + 1] = make_float4(px2[q].y, py2[q].y, pz2[q].y, 0.0f);
    dist2[q] = f32x2{1e10f, 1e10f};
  }
  if (tid == 0) {
    if (PUB) { coh_store_f(&outb[0], px2[0].x); coh_store_f(&outb[1], py2[0].x);
               coh_store_f(&outb[2], pz2[0].x); }
    else     { outb[0] = px2[0].x; outb[1] = py2[0].x; outb[2] = pz2[0].x; }
  }
  __syncthreads();
  float cx = S.p[0].x, cy = S.p[0].y, cz = S.p[0].z;

#pragma unroll 1
  for (int s = 1; s < NP; ++s) {
    const int p = s & 1;
    float bv = -1.0f; int bi = 0;
    {
#pragma clang fp contract(off)
      const f32x2 c2x = f32x2{cx, cx};
      const f32x2 c2y = f32x2{cy, cy};
      const f32x2 c2z = f32x2{cz, cz};
#pragma unroll
      for (int q = 0; q < 8; ++q) {
        f32x2 dx = px2[q] - c2x;             // v_pk_add (neg) : exact per half
        f32x2 dy = py2[q] - c2y;
        f32x2 dz = pz2[q] - c2z;
        f32x2 xx = dx * dx;                  // v_pk_mul
        f32x2 yy = dy * dy;
        f32x2 zz = dz * dz;
        f32x2 ss = (xx + yy) + zz;           // v_pk_add x2, reference order
        float dm0 = fminf(dist2[q].x, ss.x);
        float dm1 = fminf(dist2[q].y, ss.y);
        dist2[q].x = dm0; dist2[q].y = dm1;
        bool g0 = dm0 > bv;                  // strict: lowest index on ties
        bi = g0 ? (i0 + 2*q + 0) : bi;
        bv = g0 ? dm0 : bv;
        bool g1 = dm1 > bv;
        bi = g1 ? (i0 + 2*q + 1) : bi;
        bv = g1 ? dm1 : bv;
      }
    }
    u64 pk = ((u64)__float_as_uint(bv) << 32) | (unsigned)(8191 - bi);
    pk = dpp_max_u64<0x111>(pk);             // row_shr:1
    pk = dpp_max_u64<0x112>(pk);             // row_shr:2
    pk = dpp_max_u64<0x114>(pk);             // row_shr:4
    pk = dpp_max_u64<0x118>(pk);             // row_shr:8
    pk = dpp_max_u64<0x142>(pk);             // row_bcast:15
    pk = dpp_max_u64<0x143>(pk);             // row_bcast:31  -> max in lane 63
    if (lane == 63) S.red[p][wid] = pk;
    __syncthreads();                         // the ONE barrier per step
    u64 t0=S.red[p][0], t1=S.red[p][1], t2=S.red[p][2], t3=S.red[p][3];
    u64 t4=S.red[p][4], t5=S.red[p][5], t6=S.red[p][6], t7=S.red[p][7];
    t0=(t1>t0)?t1:t0; t2=(t3>t2)?t3:t2; t4=(t5>t4)?t5:t4; t6=(t7>t6)?t7:t6;
    t0=(t2>t0)?t2:t0; t4=(t6>t4)?t6:t4;
    t0=(t4>t0)?t4:t0;
    const int ri = 8191 - (int)((unsigned)(t0 & 0xffffffffu));
    const float4 c = S.p[ri];                // single b128 broadcast
    cx = c.x; cy = c.y; cz = c.z;
    if (tid == 0) {
      const size_t o = (size_t)s * 3;
      if (PUB) {
        coh_store_f(&outb[o+0], cx); coh_store_f(&outb[o+1], cy);
        coh_store_f(&outb[o+2], cz);
        if ((s & 7) == 7) {
          asm volatile("s_waitcnt vmcnt(0)" ::: "memory");  // data stores visible
          __hip_atomic_store(prog_b, s + 1, __ATOMIC_RELAXED,
                             __HIP_MEMORY_SCOPE_AGENT);
        }
      } else {
        outb[o+0]=cx; outb[o+1]=cy; outb[o+2]=cz;
      }
    }
  }
  if (PUB && tid == 0) {
    asm volatile("s_waitcnt vmcnt(0)" ::: "memory");
    __hip_atomic_store(prog_b, NP, __ATOMIC_RELAXED, __HIP_MEMORY_SCOPE_AGENT);
  }
}

// ---------------- one-query KNN (one wave) -----------------------------------
__device__ __forceinline__ void knn_one(const float4* __restrict__ s_pts,
    const float qx, const float qy, const float qz, const int lane,
    int* __restrict__ gout, int* __restrict__ lout) {
  const float qn = addrn(addrn(mulrn(qx,qx), mulrn(qy,qy)), mulrn(qz,qz));
  float bd = (lane < 16) ? 1e30f : -1e30f;
  int   bi = 0;
  float r = 1e30f;
#pragma unroll 1
  for (int c0 = 0; c0 < NPTS; c0 += 64) {
    float4 p = s_pts[c0 + lane];
    float dot = addrn(addrn(mulrn(qx, p.x), mulrn(qy, p.y)), mulrn(qz, p.z));
    float dd = addrn(addrn(mulrn(-2.0f, dot), qn), p.w);
    u64 m = __ballot(dd < r);
    while (m) {
      int src = __builtin_ctzll(m);
      m &= (m - 1);
      float v = __shfl(dd, src, 64);
      if (v < r) {
        int vi = c0 + src;
        float bdn = __shfl_down(bd, 1, 64);
        int   bin_ = __shfl_down(bi, 1, 64);
        bool c1 = bdn > v;
        bool c2 = bd > v;
        float nb  = c1 ? bdn  : (c2 ? v  : bd);
        int   nbi = c1 ? bin_ : (c2 ? vi : bi);
        bd = (lane < 16) ? nb  : -1e30f;
        bi = (lane < 16) ? nbi : bi;
        r = __shfl(bd, 0, 64);
      }
    }
  }
  if (lane < 16) {
    if (gout) gout[lane] = bi;
    if (lout) lout[lane] = bi;
  }
}

// ---------------- MEGA: producers + consumers + in-kernel stats/finalize -----
// prog[0..7]  : per-batch FPS progress
// prog[8]     : consumer arrival counter (all tickets + partials done)
// prog[9]     : scale/bias-ready flag
__global__ __launch_bounds__(512) void k_mega(const float* __restrict__ xyz,
    const float* __restrict__ feat, const float* __restrict__ W,
    const float* __restrict__ gamma, const float* __restrict__ beta,
    float* __restrict__ out_xyz, float* __restrict__ out_nf,
    int* __restrict__ knn,
    float* __restrict__ part_sum, float* __restrict__ part_sq,
    float* __restrict__ hmax_buf, float* __restrict__ hmin_buf,
    float* __restrict__ scale, float* __restrict__ bias,
    int* __restrict__ prog) {
  __shared__ MegaSm sm;
  const int tid = threadIdx.x;
  if (blockIdx.x < NB) {
    const int b = blockIdx.x;
    fps_body<true>(xyz + (size_t)b * NPTS * 3, out_xyz + (size_t)b * NP * 3,
                   sm.f, &prog[b], tid);
    return;
  }
  // ---- consumer ----
  const int c = blockIdx.x - NB;           // 0..247
  const int b = c & 7;                     // fixed batch per block
  ConsSm& S = sm.c;
  const float* base = xyz + (size_t)b * NPTS * 3;
  for (int i = tid; i < NPTS; i += 512) {
    float x = base[i*3+0], y = base[i*3+1], z = base[i*3+2];
    float n = addrn(addrn(mulrn(x,x), mulrn(y,y)), mulrn(z,z));
    S.pts[i] = make_float4(x, y, z, n);
  }
  const int d = tid & 255;
  const int h = tid >> 8;                  // half 0/1
  float w[132];
#pragma unroll
  for (int cc = 0; cc < 132; ++cc) {
    if (cc < 128)      w[cc] = W[(size_t)(3 + cc) * COUT + d];
    else if (cc < 131) w[cc] = W[(size_t)(cc - 128) * COUT + d];
    else               w[cc] = 0.0f;
  }
  float psum = 0.0f, psq = 0.0f;
  const int lane = tid & 63;
  const int wv = tid >> 6;                 // 0..7
  __syncthreads();
#pragma unroll 1
  for (int t = c; t < NTICK; t += CONS) {
    const int g = t >> 3;                  // qgroup; (t&7)==b by construction
    const int need = g * 8 + 8;
    if (tid == 0) {
      while (__hip_atomic_load(&prog[b], __ATOMIC_RELAXED,
                               __HIP_MEMORY_SCOPE_AGENT) < need)
        __builtin_amdgcn_s_sleep(16);
    }
    __syncthreads();
    {   // knn: one query per wave; query coords via coherent loads
      const int gq = b * NP + g * 8 + wv;
      const float qx = coh_load_f(&out_xyz[(size_t)gq*3+0]);
      const float qy = coh_load_f(&out_xyz[(size_t)gq*3+1]);
      const float qz = coh_load_f(&out_xyz[(size_t)gq*3+2]);
      knn_one(S.pts, qx, qy, qz, lane, &knn[(size_t)gq * KNN_K], &S.sknn[wv][0]);
    }
    __syncthreads();
    // gemm mode0 for the 8 queries: half h does 4
#pragma unroll 1
    for (int i = 0; i < 4; ++i) {
      const int ql = h * 4 + i;
      const int gq = b * NP + g * 8 + ql;
      {
        const int row = d >> 4, sub = d & 15;
        const int nidx = S.sknn[ql][row];
        const float* frow = feat + ((size_t)b * NPTS + nidx) * CIN;
        const float4 a0 = *(const float4*)(frow + sub * 8);
        const float4 a1 = *(const float4*)(frow + sub * 8 + 4);
        *(float4*)&S.sg[h][row][sub * 8]     = a0;
        *(float4*)&S.sg[h][row][sub * 8 + 4] = a1;
        if (sub == 0) {
          const float gx = xyz[((size_t)b * NPTS + nidx) * 3 + 0];
          const float gy = xyz[((size_t)b * NPTS + nidx) * 3 + 1];
          const float gz = xyz[((size_t)b * NPTS + nidx) * 3 + 2];
          const float qx = coh_load_f(&out_xyz[(size_t)gq*3+0]);
          const float qy = coh_load_f(&out_xyz[(size_t)gq*3+1]);
          const float qz = coh_load_f(&out_xyz[(size_t)gq*3+2]);
          *(float4*)&S.sg[h][row][128] = make_float4(gx-qx, gy-qy, gz-qz, 0.0f);
        }
      }
      __syncthreads();
      float hmax = -1e30f, hmin = 1e30f;
#pragma unroll 1
      for (int k = 0; k < 16; ++k) {
        float a0 = 0.f, a1 = 0.f, a2 = 0.f, a3 = 0.f;
#pragma unroll
        for (int c4 = 0; c4 < 33; ++c4) {
          float4 gg = *(const float4*)&S.sg[h][k][c4 * 4];
          a0 = fmaf(gg.x, w[c4 * 4 + 0], a0);
          a1 = fmaf(gg.y, w[c4 * 4 + 1], a1);
          a2 = fmaf(gg.z, w[c4 * 4 + 2], a2);
          a3 = fmaf(gg.w, w[c4 * 4 + 3], a3);
        }
        float hv = (a0 + a1) + (a2 + a3);
        psum += hv; psq = fmaf(hv, hv, psq);
        hmax = fmaxf(hmax, hv); hmin = fminf(hmin, hv);
      }
      hmax_buf[(size_t)gq * COUT + d] = hmax;   // block-local: re-read below
      hmin_buf[(size_t)gq * COUT + d] = hmin;
      __syncthreads();
    }
  }
  // publish partials (sc1 -> LLC) and arrive at the software barrier
  coh_store_f(&part_sum[((size_t)c * 2 + h) * COUT + d], psum);
  coh_store_f(&part_sq [((size_t)c * 2 + h) * COUT + d], psq);
  asm volatile("s_waitcnt vmcnt(0)" ::: "memory");   // wave's stores at LLC
  __syncthreads();
  if (tid == 0)
    __hip_atomic_fetch_add(&prog[8], 1, __ATOMIC_RELAXED,
                           __HIP_MEMORY_SCOPE_AGENT);
  // consumer 0 computes scale/bias once all partials are published
  if (c == 0) {
    if (tid == 0) {
      while (__hip_atomic_load(&prog[8], __ATOMIC_RELAXED,
                               __HIP_MEMORY_SCOPE_AGENT) < CONS)
        __builtin_amdgcn_s_sleep(16);
    }
    __syncthreads();
    if (tid < 256) {
      float s = 0.0f, q = 0.0f;
#pragma unroll 1
      for (int r = 0; r < CONS * 2; ++r) {
        s += coh_load_f(&part_sum[(size_t)r * COUT + tid]);
        q += coh_load_f(&part_sq [(size_t)r * COUT + tid]);
      }
      const float inv = 1.0f / 262144.0f;
      float mean = s * inv;
      float var = q * inv - mean * mean;
      float scv = gamma[tid] / sqrtf(var + 1e-5f);
      coh_store_f(&scale[tid], scv);
      coh_store_f(&bias[tid], beta[tid] - mean * scv);
    }
    asm volatile("s_waitcnt vmcnt(0)" ::: "memory");
    __syncthreads();
    if (tid == 0)
      __hip_atomic_store(&prog[9], 1, __ATOMIC_RELAXED,
                         __HIP_MEMORY_SCOPE_AGENT);
  }
  // all consumers: wait for scale/bias, then finalize OWN rows (L2-local)
  if (tid == 0) {
    while (__hip_atomic_load(&prog[9], __ATOMIC_RELAXED,
                             __HIP_MEMORY_SCOPE_AGENT) < 1)
      __builtin_amdgcn_s_sleep(16);
  }
  __syncthreads();
  const float sc = coh_load_f(&scale[d]);
  const float bb = coh_load_f(&bias[d]);
#pragma unroll 1
  for (int t = c; t < NTICK; t += CONS) {
    const int g = t >> 3;
#pragma unroll
    for (int i = 0; i < 4; ++i) {
      const int gq = b * NP + g * 8 + h * 4 + i;
      const float hx = hmax_buf[(size_t)gq * COUT + d];
      const float hn = hmin_buf[(size_t)gq * COUT + d];
      const float hsel = (sc >= 0.0f) ? hx : hn;
      out_nf[(size_t)gq * COUT + d] = fmaxf(fmaf(sc, hsel, bb), 0.0f);
    }
  }
}

// ---------------- init: zero progress counters + barrier + flag --------------
__global__ void k_init(int* __restrict__ prog) {
  if (threadIdx.x < 16) prog[threadIdx.x] = 0;
}

// ---------------- standalone fallback kernels --------------------------------
__global__ __launch_bounds__(512) void k_fps(const float* __restrict__ xyz,
                                             float* __restrict__ out_xyz) {
  __shared__ FpsSm S;
  fps_body<false>(xyz + (size_t)blockIdx.x * NPTS * 3,
                  out_xyz + (size_t)blockIdx.x * NP * 3, S, nullptr, threadIdx.x);
}

__global__ __launch_bounds__(512) void k_knn(const float* __restrict__ xyz,
                                             const float* __restrict__ new_xyz,
                                             int* __restrict__ knn) {
  __shared__ float4 s_pts[NPTS];   // 128 KB
  const int gq0 = blockIdx.x * 64;
  const int b = gq0 >> 11;
  const float* base = xyz + (size_t)b * NPTS * 3;
  for (int i = threadIdx.x; i < NPTS; i += 512) {
    float x = base[i*3+0], y = base[i*3+1], z = base[i*3+2];
    float n = addrn(addrn(mulrn(x,x), mulrn(y,y)), mulrn(z,z));
    s_pts[i] = make_float4(x, y, z, n);
  }
  __syncthreads();
  const int wave = threadIdx.x >> 6;
  const int lane = threadIdx.x & 63;
#pragma unroll 1
  for (int qi = 0; qi < 8; ++qi) {
    const int gq = gq0 + wave * 8 + qi;
    knn_one(s_pts, new_xyz[(size_t)gq*3+0], new_xyz[(size_t)gq*3+1],
            new_xyz[(size_t)gq*3+2], lane, &knn[(size_t)gq * KNN_K], nullptr);
  }
}

__global__ __launch_bounds__(256) void k_gemm(const float* __restrict__ feat,
    const float* __restrict__ xyz, const float* __restrict__ new_xyz,
    const int* __restrict__ knn, const float* __restrict__ W,
    float* __restrict__ part_sum, float* __restrict__ part_sq,
    float* __restrict__ hmax_buf, float* __restrict__ hmin_buf,
    const float* __restrict__ scale, const float* __restrict__ bias,
    float* __restrict__ out, int mode) {
  __shared__ float sg[16][132];
  const int d = threadIdx.x;
  float w[132];
#pragma unroll
  for (int c = 0; c < 132; ++c) {
    if (c < 128)      w[c] = W[(size_t)(3 + c) * COUT + d];
    else if (c < 131) w[c] = W[(size_t)(c - 128) * COUT + d];
    else              w[c] = 0.0f;
  }
  float psum = 0.0f, psq = 0.0f;
  float sc = 0.0f, bb = 0.0f;
  if (mode == 1) { sc = scale[d]; bb = bias[d]; }
#pragma unroll 1
  for (int i = 0; i < FB_GEMM_QPB; ++i) {
    const int gq = blockIdx.x * FB_GEMM_QPB + i;
    const int b = gq >> 11;
    {
      const int row = d >> 4, sub = d & 15;
      const int nidx = knn[(size_t)gq * KNN_K + row];
      const float* frow = feat + ((size_t)b * NPTS + nidx) * CIN;
      const float4 a0 = *(const float4*)(frow + sub * 8);
      const float4 a1 = *(const float4*)(frow + sub * 8 + 4);
      *(float4*)&sg[row][sub * 8]     = a0;
      *(float4*)&sg[row][sub * 8 + 4] = a1;
      if (sub == 0) {
        const float gx = xyz[((size_t)b * NPTS + nidx) * 3 + 0];
        const float gy = xyz[((size_t)b * NPTS + nidx) * 3 + 1];
        const float gz = xyz[((size_t)b * NPTS + nidx) * 3 + 2];
        const float qx = new_xyz[(size_t)gq * 3 + 0];
        const float qy = new_xyz[(size_t)gq * 3 + 1];
        const float qz = new_xyz[(size_t)gq * 3 + 2];
        *(float4*)&sg[row][128] = make_float4(gx - qx, gy - qy, gz - qz, 0.0f);
      }
    }
    __syncthreads();
    float hmax = -1e30f, hmin = 1e30f;
#pragma unroll 1
    for (int k = 0; k < 16; ++k) {
      float a0 = 0.f, a1 = 0.f, a2 = 0.f, a3 = 0.f;
#pragma unroll
      for (int c4 = 0; c4 < 33; ++c4) {
        float4 g = *(const float4*)&sg[k][c4 * 4];
        a0 = fmaf(g.x, w[c4 * 4 + 0], a0);
        a1 = fmaf(g.y, w[c4 * 4 + 1], a1);
        a2 = fmaf(g.z, w[c4 * 4 + 2], a2);
        a3 = fmaf(g.w, w[c4 * 4 + 3], a3);
      }
      float hv = (a0 + a1) + (a2 + a3);
      if (mode == 0) { psum += hv; psq = fmaf(hv, hv, psq); }
      hmax = fmaxf(hmax, hv); hmin = fminf(hmin, hv);
    }
    if (mode == 0) {
      if (hmax_buf) {
        hmax_buf[(size_t)gq * COUT + d] = hmax;
        hmin_buf[(size_t)gq * COUT + d] = hmin;
      }
    } else {
      float hsel = (sc >= 0.0f) ? hmax : hmin;
      out[(size_t)gq * COUT + d] = fmaxf(fmaf(sc, hsel, bb), 0.0f);
    }
    __syncthreads();
  }
  if (mode == 0) {
    part_sum[(size_t)blockIdx.x * COUT + d] = psum;
    part_sq [(size_t)blockIdx.x * COUT + d] = psq;
  }
}

// ---------------- stats fold (fallback) --------------------------------------
__global__ __launch_bounds__(256) void k_stats(const float* __restrict__ part_sum,
    const float* __restrict__ part_sq, const float* __restrict__ gamma,
    const float* __restrict__ beta, float* __restrict__ scale,
    float* __restrict__ bias, int nrows) {
  const int d = threadIdx.x;
  float s = 0.0f, q = 0.0f;
  for (int bl = 0; bl < nrows; ++bl) {
    s += part_sum[(size_t)bl * COUT + d];
    q += part_sq[(size_t)bl * COUT + d];
  }
  const float inv = 1.0f / 262144.0f;
  float mean = s * inv;
  float var = q * inv - mean * mean;
  float scv = gamma[d] / sqrtf(var + 1e-5f);
  scale[d] = scv;
  bias[d] = beta[d] - mean * scv;
}

// ---------------- elementwise finalize (fallback) ----------------------------
__global__ __launch_bounds__(256) void k_final(const float* __restrict__ hmax_buf,
    const float* __restrict__ hmin_buf, const float* __restrict__ scale,
    const float* __restrict__ bias, float* __restrict__ out) {
  const int e4 = (blockIdx.x * 256 + threadIdx.x) * 4;
  const int d0 = e4 & (COUT - 1);
  const float4 hx = *(const float4*)&hmax_buf[e4];
  const float4 hn = *(const float4*)&hmin_buf[e4];
  const float4 sc = *(const float4*)&scale[d0];
  const float4 bb = *(const float4*)&bias[d0];
  float4 o;
  o.x = fmaxf(fmaf(sc.x, (sc.x >= 0.f) ? hx.x : hn.x, bb.x), 0.f);
  o.y = fmaxf(fmaf(sc.y, (sc.y >= 0.f) ? hx.y : hn.y, bb.y), 0.f);
  o.z = fmaxf(fmaf(sc.z, (sc.z >= 0.f) ? hx.z : hn.z, bb.z), 0.f);
  o.w = fmaxf(fmaf(sc.w, (sc.w >= 0.f) ? hx.w : hn.w, bb.w), 0.f);
  *(float4*)&out[e4] = o;
}

extern "C" void kernel_launch(void* const* d_in, const int* in_sizes, int n_in,
                              void* d_out, int out_size, void* d_ws, size_t ws_size,
                              hipStream_t stream) {
  const float* xyz   = (const float*)d_in[0];
  const float* feat  = (const float*)d_in[1];
  const float* W     = (const float*)d_in[2];
  const float* gamma = (const float*)d_in[3];
  const float* beta  = (const float*)d_in[4];
  float* out_xyz = (float*)d_out;
  float* out_nf  = out_xyz + (size_t)NB * NP * 3;

  // workspace layout (~35.65 MB)
  char* ws = (char*)d_ws;
  int*   knn      = (int*)ws;                                        // 1 MB
  float* hmax_buf = (float*)(ws + (1 << 20));                        // 16.78 MB
  float* hmin_buf = (float*)(ws + (1 << 20) + (size_t)GQ_TOTAL*COUT*4);
  char*  ws3      = ws + (1 << 20) + 2ull * GQ_TOTAL * COUT * 4;
  float* part_sum = (float*)ws3;                                     // 512 KB
  float* part_sq  = (float*)(ws3 + (size_t)FB_GEMM_BLOCKS * COUT * 4);
  int*   prog     = (int*)(ws3 + 2ull * FB_GEMM_BLOCKS * COUT * 4);  // 64 B
  float* scale    = (float*)((char*)prog + 64);
  float* bias     = scale + COUT;
  const size_t need = (1ull << 20) + 2ull * GQ_TOTAL * COUT * 4
                    + 2ull * FB_GEMM_BLOCKS * COUT * 4 + 64 + 2 * COUT * 4;

  bool mega_ok = false;
  if (ws_size >= need) {
    hipLaunchKernelGGL(k_init, dim3(1), dim3(64), 0, stream, prog);
    void* args[] = {(void*)&xyz, (void*)&feat, (void*)&W,
                    (void*)&gamma, (void*)&beta,
                    (void*)&out_xyz, (void*)&out_nf, (void*)&knn,
                    (void*)&part_sum, (void*)&part_sq,
                    (void*)&hmax_buf, (void*)&hmin_buf,
                    (void*)&scale, (void*)&bias, (void*)&prog};
    hipError_t e = hipLaunchCooperativeKernel((const void*)k_mega, dim3(NB + CONS),
                                              dim3(512), args, 0, stream);
    mega_ok = (e == hipSuccess);
  }
  if (!mega_ok) {
    // sequential fallback (proven path)
    hipLaunchKernelGGL(k_fps, dim3(NB), dim3(512), 0, stream, xyz, out_xyz);
    hipLaunchKernelGGL(k_knn, dim3(256), dim3(512), 0, stream, xyz, out_xyz, knn);
    if (ws_size >= need) {
      hipLaunchKernelGGL(k_gemm, dim3(FB_GEMM_BLOCKS), dim3(256), 0, stream, feat,
                         xyz, out_xyz, knn, W, part_sum, part_sq, hmax_buf,
                         hmin_buf, (const float*)nullptr, (const float*)nullptr,
                         (float*)nullptr, 0);
      hipLaunchKernelGGL(k_stats, dim3(1), dim3(256), 0, stream, part_sum, part_sq,
                         gamma, beta, scale, bias, FB_GEMM_BLOCKS);
      hipLaunchKernelGGL(k_final, dim3(GQ_TOTAL * COUT / 1024), dim3(256), 0,
                         stream, hmax_buf, hmin_buf, scale, bias, out_nf);
    } else {
      float* f_ps = (float*)(ws + (1 << 20));
      float* f_pq = f_ps + FB_GEMM_BLOCKS * COUT;
      float* f_sc = f_pq + FB_GEMM_BLOCKS * COUT;
      float* f_bb = f_sc + COUT;
      hipLaunchKernelGGL(k_gemm, dim3(FB_GEMM_BLOCKS), dim3(256), 0, stream, feat,
                         xyz, out_xyz, knn, W, f_ps, f_pq, (float*)nullptr,
                         (float*)nullptr, (const float*)nullptr,
                         (const float*)nullptr, (float*)nullptr, 0);
      hipLaunchKernelGGL(k_stats, dim3(1), dim3(256), 0, stream, f_ps, f_pq,
                         gamma, beta, f_sc, f_bb, FB_GEMM_BLOCKS);
      hipLaunchKernelGGL(k_gemm, dim3(FB_GEMM_BLOCKS), dim3(256), 0, stream, feat,
                         xyz, out_xyz, knn, W, (float*)nullptr, (float*)nullptr,
                         (float*)nullptr, (float*)nullptr, f_sc, f_bb, out_nf, 1);
    }
  }
}